// Round 6
// baseline (259.127 us; speedup 1.0000x reference)
//
#include <hip/hip_runtime.h>

// Conv2d via implicit-GEMM MFMA: input (64,8,256,256) f32, filter (8,8,3,3)
// OIHW, VALID, stride 1 -> out (64,8,254,254) f32.
//
// mfma_f32_16x16x32_f16: M = out-channel m (8 valid of 16), N = 16 px,
// K = 96 = 3 chunks of 32. k-slot (g=lane>>4, j): q = kk*4+g (q=r*3+s,
// valid q<=8), c = j. A zeroed for q>8 / m>=8. Same convention as the
// refcheck-passed round-2..5 kernels; R5's staging/swizzle kept verbatim.
//
// Round-6 change: OCCUPANCY. R5 fixed the traffic shape (wide dense VMEM,
// 2.13 TB/s) but sat at 18% occupancy (80 KB LDS -> 2 blocks/CU, grid 512
// = exactly 2/CU, nothing queued); per-CU issue accounting shows ~75% of
// cycles are uncovered waits. This round keeps the traffic machinery and
// doubles residency:
//  - LDS 80 -> 48 KB: 2-slot input ring (32 KB) + px-batched out-buffer
//    (16 KB: 8 m x 128 px per wave, stores in two half-row batches).
//    2-slot ring => barrier BEFORE ring write + barrier after (2/step).
//  - grid 512 -> 1024 (16-row strips, 4 steps/block): 3 blocks/CU resident
//    (launch_bounds(256,3)) + 1 queued -> 12 waves/CU vs 8.

typedef _Float16 half8 __attribute__((ext_vector_type(8)));
typedef float floatx4 __attribute__((ext_vector_type(4)));

#define SLOT_H 8192   // halfs per 4-row slot (4 rows * 256 px * 8 c = 16 KB)

__global__ __launch_bounds__(256, 3)
void conv2d_mfma_kernel(const float* __restrict__ inp,
                        const float* __restrict__ filt,
                        float* __restrict__ out) {
    __shared__ __align__(16) _Float16 s_in[2 * SLOT_H + 32];  // 32832 B
    __shared__ __align__(16) float    s_out[4 * 1024];        // 16384 B

    const int tid    = threadIdx.x;
    const int ystrip = blockIdx.x * 16;   // 0,16,...,240
    const int n      = blockIdx.y;

    const float* in_n  = inp + (size_t)n * (8 * 256 * 256);
    float*       out_n = out + (size_t)n * (8 * 254 * 254);

    const int lane = tid & 63;
    const int w    = tid >> 6;    // wave 0..3 (staging row / output row owner)
    const int lx   = lane & 15;   // A: row m ; B/D: col pixel
    const int g    = lane >> 4;   // k-slot group / D row group
    const int lx4  = lane;        // staging: float4 index within row

    // ---- A-fragments + swizzled per-lane read offsets (verbatim R5) ----
    half8 afrag[3];
    int   roff[3];
    int   loH[3][4];   // half-index offset within a row, per kk per (xg&3)
    #pragma unroll
    for (int kk = 0; kk < 3; ++kk) {
        int q  = kk * 4 + g;                 // 0..11
        int qa = q > 8 ? 8 : q;              // clamp for address only
        roff[kk] = qa / 3;
        int soff = qa - roff[kk] * 3;
        int q0   = lx + soff;                // 0..17: pixel offset in 16-grp
        int e    = (q0 & 3) ^ ((q0 >> 2) & 3);
        int q0b  = q0 >> 4;                  // crosses into next group
        int baseH = (q0 >> 2) * 32;          // quad slot, halfs
        #pragma unroll
        for (int j = 0; j < 4; ++j)          // j = xg & 3
            loH[kk][j] = baseH + ((e ^ ((j + q0b) & 3)) << 3);
        half8 a = {};
        if (q <= 8 && lx < 8) {
            #pragma unroll
            for (int j = 0; j < 8; ++j)      // filt[m][c][r][s] = m*72+c*9+q
                a[j] = (_Float16)filt[lx * 72 + j * 9 + q];
        }
        afrag[kk] = a;
    }

    // ---- staging (verbatim R5 mechanics, chunk = 4 strip rows) ----
    auto load_chunk = [&](int ck, float4* dst) {
        const int iy = ystrip + ck * 4 + w;
        if (iy < 256) {
            const float* p = in_n + iy * 256 + lx4 * 4;
            #pragma unroll
            for (int c = 0; c < 8; ++c)
                dst[c] = *reinterpret_cast<const float4*>(p + c * 65536);
        } else {
            #pragma unroll
            for (int c = 0; c < 8; ++c) dst[c] = make_float4(0.f,0.f,0.f,0.f);
        }
    };
    auto write_chunk = [&](int ck, const float4* src) {
        _Float16* base = &s_in[(ck & 1) * SLOT_H + w * 2048 + lx4 * 32];
        const int sw = (lx4 & 3) ^ ((lx4 >> 2) & 3);
        #pragma unroll
        for (int i = 0; i < 4; ++i) {
            half8 h;
            #pragma unroll
            for (int c = 0; c < 8; ++c) h[c] = (_Float16)src[c][i];
            *reinterpret_cast<half8*>(base + ((i ^ sw) << 3)) = h;
        }
    };

    float4 vv[8], vv2[8];
    load_chunk(0, vv);
    load_chunk(1, vv2);      // both prologue loads in flight together
    write_chunk(0, vv);
    write_chunk(1, vv2);
    __syncthreads();

    // ---- pipelined y-walk: 4 steps of 4 output rows ----
    for (int t = 0; t < 4; ++t) {
        if (t < 3) load_chunk(t + 2, vv);    // fly under compute(t)
        __builtin_amdgcn_sched_barrier(0);   // pin load issue before compute

        const int ro = t * 4 + w;            // this wave's strip-local row
        const int oy = ystrip + ro;

        int ab[3][4];
        #pragma unroll
        for (int kk = 0; kk < 3; ++kk) {
            int L   = ro + roff[kk];         // input row needed (0..17)
            int rbH = ((L >> 2) & 1) * SLOT_H + (L & 3) * 2048;
            #pragma unroll
            for (int j = 0; j < 4; ++j) ab[kk][j] = rbH + loH[kk][j];
        }

        const bool do_out = (g < 2) && (oy < 254);
        #pragma unroll
        for (int xh = 0; xh < 2; ++xh) {
            #pragma unroll
            for (int xgl = 0; xgl < 8; ++xgl) {
                const int xg = xh * 8 + xgl;
                floatx4 acc = {0.f, 0.f, 0.f, 0.f};
                #pragma unroll
                for (int kk = 0; kk < 3; ++kk) {
                    const half8 b = *reinterpret_cast<const half8*>(
                        &s_in[ab[kk][xg & 3] + xg * 128]);
                    acc = __builtin_amdgcn_mfma_f32_16x16x32_f16(
                              afrag[kk], b, acc, 0, 0, 0);
                }
                // D: col = lane&15 (px), row = g*4+i (m; valid g<2).
                if (do_out) {
                    #pragma unroll
                    for (int i = 0; i < 4; ++i)
                        s_out[w * 1024 + (g * 4 + i) * 128 + xgl * 16 + lx]
                            = acc[i];        // 2-way bank (g0/g1) = free
                }
            }
            // dense half-row stores: 8 m-planes x 128 px, float2/lane
            if (oy < 254) {
                const int px = xh * 128 + lane * 2;
                #pragma unroll
                for (int m = 0; m < 8; ++m) {
                    float2 q2 = *reinterpret_cast<const float2*>(
                        &s_out[w * 1024 + m * 128 + lane * 2]);
                    if (px < 254)            // px even; px<254 => px+1<=253
                        *reinterpret_cast<float2*>(
                            out_n + (size_t)m * 64516 + oy * 254 + px) = q2;
                }
            }
        }

        if (t < 3) {
            __syncthreads();                 // all waves done reading slot t&1
            write_chunk(t + 2, vv);          // overwrite slot t&1
            __syncthreads();                 // slot ready for compute(t+1)
        }
    }
}

extern "C" void kernel_launch(void* const* d_in, const int* in_sizes, int n_in,
                              void* d_out, int out_size, void* d_ws, size_t ws_size,
                              hipStream_t stream) {
    const float* inp  = (const float*)d_in[0];   // (64,8,256,256)
    const float* filt = (const float*)d_in[1];   // (8,8,3,3)
    float* outp = (float*)d_out;                 // (64,8,254,254)

    dim3 grid(16, 64, 1);
    dim3 block(256);
    conv2d_mfma_kernel<<<grid, block, 0, stream>>>(inp, filt, outp);
}